// Round 1
// baseline (817.219 us; speedup 1.0000x reference)
//
#include <hip/hip_runtime.h>
#include <math.h>

// Problem constants (from reference setup_inputs): N=8192, T=1024, K=10
#define T_TRIALS 1024
#define KOPT     10
#define NCH      16     // number of T-chunks
#define TC       64     // trials per chunk (T_TRIALS / NCH)

__device__ __forceinline__ float sigmoidf_(float x) { return 1.0f / (1.0f + expf(-x)); }

// Kernel 1: thread per (row, option). Scan all T sequentially for this option's
// independent chain; write the pre-trial value at each chunk boundary directly
// into out[row, chunk*TC, k] (that location's final value IS the checkpoint).
__global__ __launch_bounds__(320) void rw_checkpoint(
    const int* __restrict__ choices, const float* __restrict__ rewards,
    const float* __restrict__ apP, const float* __restrict__ amP,
    const float* __restrict__ ivP, float* __restrict__ out, int N)
{
    int tid = blockIdx.x * blockDim.x + threadIdx.x;
    if (tid >= N * KOPT) return;
    int row = tid / KOPT;
    int k   = tid - row * KOPT;

    float ap = sigmoidf_(apP[0]);
    float am = sigmoidf_(amP[0]);
    float v  = 100.0f * tanhf(ivP[0]);

    const int*   c = choices + (size_t)row * T_TRIALS;
    const float* r = rewards + (size_t)row * T_TRIALS;

    // Process chunks 0..NCH-2; after chunk ch, store checkpoint for chunk ch+1.
    for (int ch = 0; ch < NCH - 1; ++ch) {
        int tbase = ch * TC;
#pragma unroll 4
        for (int i = 0; i < TC; ++i) {
            int   ct = c[tbase + i];
            float rt = r[tbase + i];
            if (ct == k) {
                float pe = (rt != rt) ? 0.0f : (rt - v);   // NaN reward -> pe = 0
                float lr = (pe >= 0.0f) ? ap : am;
                v = fmaf(lr, pe, v);
            }
        }
        out[((size_t)row * T_TRIALS + (size_t)(ch + 1) * TC) * KOPT + k] = v;
    }
}

// Kernel 2: thread per (row, chunk, option). Start from checkpoint (chunk 0
// starts from iv), emit value BEFORE each trial, then conditionally update.
__global__ __launch_bounds__(320) void rw_emit(
    const int* __restrict__ choices, const float* __restrict__ rewards,
    const float* __restrict__ apP, const float* __restrict__ amP,
    const float* __restrict__ ivP, float* __restrict__ out, int N)
{
    int tid = blockIdx.x * blockDim.x + threadIdx.x;
    if (tid >= N * NCH * KOPT) return;
    int unit = tid / KOPT;            // unit = row*NCH + chunk
    int k    = tid - unit * KOPT;
    int row  = unit / NCH;
    int ch   = unit - row * NCH;

    float ap = sigmoidf_(apP[0]);
    float am = sigmoidf_(amP[0]);

    int    t0   = ch * TC;
    size_t base = ((size_t)row * T_TRIALS + t0) * KOPT + k;

    float v;
    if (ch == 0) v = 100.0f * tanhf(ivP[0]);
    else         v = out[base];       // checkpoint written by rw_checkpoint

    const int*   c = choices + (size_t)row * T_TRIALS + t0;
    const float* r = rewards + (size_t)row * T_TRIALS + t0;
    float*       o = out + base;

#pragma unroll 4
    for (int i = 0; i < TC; ++i) {
        o[i * KOPT] = v;              // emit value BEFORE this trial's update
        int   ct = c[i];
        float rt = r[i];
        if (ct == k) {
            float pe = (rt != rt) ? 0.0f : (rt - v);
            float lr = (pe >= 0.0f) ? ap : am;
            v = fmaf(lr, pe, v);
        }
    }
}

extern "C" void kernel_launch(void* const* d_in, const int* in_sizes, int n_in,
                              void* d_out, int out_size, void* d_ws, size_t ws_size,
                              hipStream_t stream)
{
    const int*   choices = (const int*)  d_in[0];
    const float* rewards = (const float*)d_in[1];
    const float* ap      = (const float*)d_in[2];
    const float* am      = (const float*)d_in[3];
    const float* iv      = (const float*)d_in[4];
    float* out = (float*)d_out;

    int N = in_sizes[0] / T_TRIALS;   // 8192

    {
        int threads = N * KOPT;
        int block   = 320;            // 5 waves; 32 (row-local, k) groups
        int grid    = (threads + block - 1) / block;
        rw_checkpoint<<<grid, block, 0, stream>>>(choices, rewards, ap, am, iv, out, N);
    }
    {
        int threads = N * NCH * KOPT;
        int block   = 320;
        int grid    = (threads + block - 1) / block;
        rw_emit<<<grid, block, 0, stream>>>(choices, rewards, ap, am, iv, out, N);
    }
}

// Round 2
// 461.391 us; speedup vs baseline: 1.7712x; 1.7712x over previous
//
#include <hip/hip_runtime.h>
#include <math.h>

// Problem constants (from reference setup_inputs): N=8192, T=1024, K=10
#define T_TRIALS 1024
#define KOPT     10
#define NCH      16     // number of T-chunks
#define TC       64     // trials per chunk
#define UPB      32     // units (row,chunk) per emit block
#define TI       16     // trials per emit tile
#define LSTRIDE  164    // 16*10 + 4 pad floats (keeps 16B alignment, rotates banks)

__device__ __forceinline__ float sigmoidf_(float x) { return 1.0f / (1.0f + expf(-x)); }

// One RW update step for option-k chain (identical arithmetic in both kernels).
#define STEP(ct, rt)                                              \
    {                                                             \
        float pe = ((rt) == (rt)) ? ((rt) - v) : 0.0f;            \
        float lr = (pe >= 0.0f) ? ap : am;                        \
        float vn = fmaf(lr, pe, v);                               \
        v = ((ct) == k) ? vn : v;                                 \
    }

#define STEP4(cv, rv) STEP((cv).x, (rv).x) STEP((cv).y, (rv).y) \
                      STEP((cv).z, (rv).z) STEP((cv).w, (rv).w)

// Kernel 1: thread per (row, option). Sequential scan over the first 15 chunks,
// dwordx4 loads with depth-2 prefetch; checkpoint for chunk ch+1 goes straight
// into out[row, (ch+1)*TC, k].
__global__ __launch_bounds__(320) void rw_checkpoint(
    const int* __restrict__ choices, const float* __restrict__ rewards,
    const float* __restrict__ apP, const float* __restrict__ amP,
    const float* __restrict__ ivP, float* __restrict__ out, int N)
{
    int tid = blockIdx.x * blockDim.x + threadIdx.x;
    if (tid >= N * KOPT) return;
    int row = tid / KOPT;
    int k   = tid - row * KOPT;

    float ap = sigmoidf_(apP[0]);
    float am = sigmoidf_(amP[0]);
    float v  = 100.0f * tanhf(ivP[0]);

    const int4*   c4 = (const int4*)  (choices + (size_t)row * T_TRIALS);
    const float4* r4 = (const float4*)(rewards + (size_t)row * T_TRIALS);

    int4   cA = c4[0]; float4 rA = r4[0];
    int4   cB = c4[1]; float4 rB = r4[1];

    for (int ch = 0; ch < NCH - 1; ++ch) {
#pragma unroll
        for (int gp = 0; gp < 8; ++gp) {       // 8 pairs of 4-trial groups = 64 trials
            int gi = ch * 16 + gp * 2;
            // prefetch two groups ahead (max gi=238 -> loads 240,241 <= 255: in-bounds)
            int4   cN1 = c4[gi + 2]; float4 rN1 = r4[gi + 2];
            int4   cN2 = c4[gi + 3]; float4 rN2 = r4[gi + 3];
            STEP4(cA, rA)
            STEP4(cB, rB)
            cA = cN1; rA = rN1; cB = cN2; rB = rN2;
        }
        out[((size_t)row * T_TRIALS + (size_t)(ch + 1) * TC) * KOPT + k] = v;
    }
}

// Kernel 2: thread per (row, chunk, option). Replays its chunk from the
// checkpoint, staging each 16-trial x 10-option tile in LDS, then the block
// cooperatively streams the tile out as float4 (640B contiguous per unit).
__global__ __launch_bounds__(320) void rw_emit(
    const int* __restrict__ choices, const float* __restrict__ rewards,
    const float* __restrict__ apP, const float* __restrict__ amP,
    const float* __restrict__ ivP, float* __restrict__ out, int N)
{
    __shared__ float lds[UPB * LSTRIDE];      // 32*164*4 = 20992 B

    int j = threadIdx.x;                      // 0..319
    int u = j / KOPT;                         // local unit 0..31
    int k = j - u * KOPT;
    int unit = blockIdx.x * UPB + u;          // global (row,chunk) unit
    int nUnits = N * NCH;
    bool active = unit < nUnits;

    int row = unit / NCH;
    int ch  = unit & (NCH - 1);

    float ap = sigmoidf_(apP[0]);
    float am = sigmoidf_(amP[0]);

    size_t base = ((size_t)row * T_TRIALS + (size_t)ch * TC) * KOPT + k;

    float v = 0.0f;
    if (active) {
        if (ch == 0) v = 100.0f * tanhf(ivP[0]);
        else         v = out[base];           // checkpoint from rw_checkpoint
    }

    const int4*   c4 = (const int4*)  (choices + (size_t)row * T_TRIALS + ch * TC);
    const float4* r4 = (const float4*)(rewards + (size_t)row * T_TRIALS + ch * TC);
    float* L = &lds[u * LSTRIDE + k];

    for (int tile = 0; tile < TC / TI; ++tile) {
        if (active) {
            int4   c0 = c4[tile * 4 + 0], c1 = c4[tile * 4 + 1],
                   c2 = c4[tile * 4 + 2], c3 = c4[tile * 4 + 3];
            float4 r0 = r4[tile * 4 + 0], r1 = r4[tile * 4 + 1],
                   r2 = r4[tile * 4 + 2], r3 = r4[tile * 4 + 3];
            // emit value BEFORE each trial's update
            L[0*KOPT] = v; STEP(c0.x, r0.x) L[1*KOPT] = v; STEP(c0.y, r0.y)
            L[2*KOPT] = v; STEP(c0.z, r0.z) L[3*KOPT] = v; STEP(c0.w, r0.w)
            L[4*KOPT] = v; STEP(c1.x, r1.x) L[5*KOPT] = v; STEP(c1.y, r1.y)
            L[6*KOPT] = v; STEP(c1.z, r1.z) L[7*KOPT] = v; STEP(c1.w, r1.w)
            L[8*KOPT] = v; STEP(c2.x, r2.x) L[9*KOPT] = v; STEP(c2.y, r2.y)
            L[10*KOPT] = v; STEP(c2.z, r2.z) L[11*KOPT] = v; STEP(c2.w, r2.w)
            L[12*KOPT] = v; STEP(c3.x, r3.x) L[13*KOPT] = v; STEP(c3.y, r3.y)
            L[14*KOPT] = v; STEP(c3.z, r3.z) L[15*KOPT] = v; STEP(c3.w, r3.w)
        }
        __syncthreads();
        // cooperative store: UPB units x 40 float4 each = 1280 float4, 320 thr x 4
#pragma unroll
        for (int w = 0; w < 4; ++w) {
            int idx = w * 320 + j;
            int uu  = idx / 40;               // local unit
            int f4  = idx - uu * 40;
            int gu  = blockIdx.x * UPB + uu;
            if (gu < nUnits) {
                int grow = gu / NCH;
                int gch  = gu & (NCH - 1);
                float4 val = *(const float4*)&lds[uu * LSTRIDE + f4 * 4];
                float* dst = out + ((size_t)grow * T_TRIALS + (size_t)gch * TC
                                    + (size_t)tile * TI) * KOPT + (size_t)f4 * 4;
                *(float4*)dst = val;
            }
        }
        __syncthreads();
    }
}

extern "C" void kernel_launch(void* const* d_in, const int* in_sizes, int n_in,
                              void* d_out, int out_size, void* d_ws, size_t ws_size,
                              hipStream_t stream)
{
    const int*   choices = (const int*)  d_in[0];
    const float* rewards = (const float*)d_in[1];
    const float* ap      = (const float*)d_in[2];
    const float* am      = (const float*)d_in[3];
    const float* iv      = (const float*)d_in[4];
    float* out = (float*)d_out;

    int N = in_sizes[0] / T_TRIALS;   // 8192

    {
        int threads = N * KOPT;
        int block   = 320;
        int grid    = (threads + block - 1) / block;
        rw_checkpoint<<<grid, block, 0, stream>>>(choices, rewards, ap, am, iv, out, N);
    }
    {
        int units = N * NCH;
        int grid  = (units + UPB - 1) / UPB;
        rw_emit<<<grid, 320, 0, stream>>>(choices, rewards, ap, am, iv, out, N);
    }
}

// Round 3
// 443.528 us; speedup vs baseline: 1.8425x; 1.0403x over previous
//
#include <hip/hip_runtime.h>
#include <math.h>

// Problem constants: N=8192 rows, T=1024 trials, K=10 options
#define T_TRIALS 1024
#define KOPT     10
#define RPB      32                  // rows per block
#define TI       16                  // trials per LDS tile
#define NTILES   (T_TRIALS / TI)     // 64
#define LSTRIDE  164                 // 16*10 + 4 pad floats (16B-aligned, rotates banks)
#define BLOCK    (RPB * KOPT)        // 320 threads = 5 waves

__device__ __forceinline__ float sigmoidf_(float x) { return 1.0f / (1.0f + expf(-x)); }

// One RW update for the option-k chain (branchless; exact f32 reference arithmetic).
#define STEP(ct, rt)                                              \
    {                                                             \
        float pe = ((rt) == (rt)) ? ((rt) - v) : 0.0f;            \
        float lr = (pe >= 0.0f) ? ap : am;                        \
        float vn = fmaf(lr, pe, v);                               \
        v = ((ct) == k) ? vn : v;                                 \
    }

// Fused single-pass kernel: thread (u,k) owns row blockIdx*32+u, option k, and
// scans all 1024 trials keeping v in a register. Emitted values (pre-update)
// are staged in double-buffered LDS tiles of 16 trials x 10 options per row,
// then the whole block streams each tile to global as coalesced float4.
__global__ __launch_bounds__(BLOCK) void rw_fused(
    const int* __restrict__ choices, const float* __restrict__ rewards,
    const float* __restrict__ apP, const float* __restrict__ amP,
    const float* __restrict__ ivP, float* __restrict__ out, int N)
{
    __shared__ float lds[2][RPB * LSTRIDE];   // 2 * 32 * 164 * 4 = 41984 B

    const int j   = threadIdx.x;
    const int u   = j / KOPT;                 // local row 0..31
    const int k   = j - u * KOPT;             // option 0..9
    int row = blockIdx.x * RPB + u;
    if (row >= N) row = N - 1;                // safety clamp (grid is exact for N=8192)

    const float ap = sigmoidf_(apP[0]);
    const float am = sigmoidf_(amP[0]);
    float v = 100.0f * tanhf(ivP[0]);

    const int4*   c4 = (const int4*)  (choices + (size_t)row * T_TRIALS);
    const float4* r4 = (const float4*)(rewards + (size_t)row * T_TRIALS);

    // Per-thread LDS write bases for the two buffers.
    float* Lw[2] = { &lds[0][u * LSTRIDE + k], &lds[1][u * LSTRIDE + k] };

    // Store-loop assignment (fixed per thread): 4 float4 per tile.
    // idx = w*320 + j -> local row uu = idx/40, vector f4 = idx%40.
    int    s_uu[4], s_f4[4];
    float* s_dst[4];
    bool   s_ok[4];
#pragma unroll
    for (int w = 0; w < 4; ++w) {
        int idx = w * BLOCK + j;
        int uu  = idx / 40;
        int f4  = idx - uu * 40;
        s_uu[w] = uu; s_f4[w] = f4;
        int grow = blockIdx.x * RPB + uu;
        s_ok[w]  = grow < N;
        if (grow >= N) grow = N - 1;
        s_dst[w] = out + (size_t)grow * T_TRIALS * KOPT + (size_t)f4 * 4;
    }

    // Prefetch tile 0.
    int4   ca0 = c4[0], ca1 = c4[1], ca2 = c4[2], ca3 = c4[3];
    float4 ra0 = r4[0], ra1 = r4[1], ra2 = r4[2], ra3 = r4[3];

    for (int tile = 0; tile < NTILES; ++tile) {
        // Prefetch next tile (wraps on the last iteration; values unused then).
        int nx = ((tile + 1) & (NTILES - 1)) * 4;
        int4   cb0 = c4[nx + 0], cb1 = c4[nx + 1], cb2 = c4[nx + 2], cb3 = c4[nx + 3];
        float4 rb0 = r4[nx + 0], rb1 = r4[nx + 1], rb2 = r4[nx + 2], rb3 = r4[nx + 3];

        // Emit (pre-update) + update, 16 trials into LDS buffer tile&1.
        float* L = Lw[tile & 1];
        L[ 0*KOPT] = v; STEP(ca0.x, ra0.x) L[ 1*KOPT] = v; STEP(ca0.y, ra0.y)
        L[ 2*KOPT] = v; STEP(ca0.z, ra0.z) L[ 3*KOPT] = v; STEP(ca0.w, ra0.w)
        L[ 4*KOPT] = v; STEP(ca1.x, ra1.x) L[ 5*KOPT] = v; STEP(ca1.y, ra1.y)
        L[ 6*KOPT] = v; STEP(ca1.z, ra1.z) L[ 7*KOPT] = v; STEP(ca1.w, ra1.w)
        L[ 8*KOPT] = v; STEP(ca2.x, ra2.x) L[ 9*KOPT] = v; STEP(ca2.y, ra2.y)
        L[10*KOPT] = v; STEP(ca2.z, ra2.z) L[11*KOPT] = v; STEP(ca2.w, ra2.w)
        L[12*KOPT] = v; STEP(ca3.x, ra3.x) L[13*KOPT] = v; STEP(ca3.y, ra3.y)
        L[14*KOPT] = v; STEP(ca3.z, ra3.z) L[15*KOPT] = v; STEP(ca3.w, ra3.w)

        __syncthreads();   // writes of buf (tile&1) visible; also fences the
                           // buf reuse hazard one iteration later (WAR covered
                           // because reads below complete before this barrier
                           // on the NEXT iteration's opposite buffer).

        // Cooperative coalesced store of this tile: 32 rows x 160 floats.
        const float* Ls = &lds[tile & 1][0];
#pragma unroll
        for (int w = 0; w < 4; ++w) {
            float4 val = *(const float4*)(Ls + s_uu[w] * LSTRIDE + s_f4[w] * 4);
            if (s_ok[w]) *(float4*)s_dst[w] = val;
            s_dst[w] += TI * KOPT;          // advance 160 floats to next tile
        }

        ca0 = cb0; ca1 = cb1; ca2 = cb2; ca3 = cb3;
        ra0 = rb0; ra1 = rb1; ra2 = rb2; ra3 = rb3;
    }
}

extern "C" void kernel_launch(void* const* d_in, const int* in_sizes, int n_in,
                              void* d_out, int out_size, void* d_ws, size_t ws_size,
                              hipStream_t stream)
{
    const int*   choices = (const int*)  d_in[0];
    const float* rewards = (const float*)d_in[1];
    const float* ap      = (const float*)d_in[2];
    const float* am      = (const float*)d_in[3];
    const float* iv      = (const float*)d_in[4];
    float* out = (float*)d_out;

    int N    = in_sizes[0] / T_TRIALS;        // 8192
    int grid = (N + RPB - 1) / RPB;           // 256 blocks -> 1 per CU

    rw_fused<<<grid, BLOCK, 0, stream>>>(choices, rewards, ap, am, iv, out, N);
}